// Round 1
// baseline (4020.458 us; speedup 1.0000x reference)
//
#include <hip/hip_runtime.h>
#include <stdint.h>

// Problem: B=64, T=256, F_IN=2048, H=1024, 3H=3072, M=B*T=16384.
// d_in: 0 input_var f32[64,256,2048], 1 input_lengths i32[64], 2 W_p f32[1024,2048],
//       3 b_p f32[1024], 4 w_ih f32[3072,1024], 5 w_hh f32[3072,1024],
//       6 b_ih f32[3072], 7 b_hh f32[3072]
// d_out: output f32[64,256,1024] then hidden f32[64,1024]

typedef __bf16 bfx8 __attribute__((ext_vector_type(8)));
typedef float  f32x4 __attribute__((ext_vector_type(4)));

// ---------------- fp32 -> bf16 conversion (8 elems/thread) ----------------
__global__ void cvt_bf16(const float* __restrict__ in, __bf16* __restrict__ out, int n8) {
    for (int i = blockIdx.x * blockDim.x + threadIdx.x; i < n8; i += gridDim.x * blockDim.x) {
        float4 a = ((const float4*)in)[2 * i];
        float4 b = ((const float4*)in)[2 * i + 1];
        union { __bf16 h[8]; uint4 v; } u;
        u.h[0] = (__bf16)a.x; u.h[1] = (__bf16)a.y; u.h[2] = (__bf16)a.z; u.h[3] = (__bf16)a.w;
        u.h[4] = (__bf16)b.x; u.h[5] = (__bf16)b.y; u.h[6] = (__bf16)b.z; u.h[7] = (__bf16)b.w;
        ((uint4*)out)[i] = u.v;
    }
}

// ---------------- async global->LDS 16B ----------------
__device__ __forceinline__ void g2l16(const void* g, void* l) {
    __builtin_amdgcn_global_load_lds(
        (__attribute__((address_space(1))) void*)g,
        (__attribute__((address_space(3))) void*)l,
        16, 0, 0);
}

// ---------------- m97-style bf16 GEMM: C[M][N] = A[M][K] * W[N][K]^T + bias ----------------
// 128x128 tile, BK=32, 256 threads = 4 waves in 2x2, each wave 64x64 (4x4 MFMA tiles).
template <bool OUTBF16>
__global__ __launch_bounds__(256)
void gemm_bt(const __bf16* __restrict__ A, const __bf16* __restrict__ W,
             const float* __restrict__ bias, void* __restrict__ C,
             int M, int N, int K)
{
    __shared__ __bf16 As[128 * 32];
    __shared__ __bf16 Ws[128 * 32];
    const int tid  = threadIdx.x;
    const int wave = tid >> 6, lane = tid & 63;
    const int q = lane >> 4, r15 = lane & 15;
    const int n0 = blockIdx.x << 7, m0 = blockIdx.y << 7;
    const int wm = (wave >> 1) << 6, wn = (wave & 1) << 6;
    const size_t Ks = (size_t)K;
    f32x4 acc[4][4] = {};

    for (int k0 = 0; k0 < K; k0 += 32) {
        __syncthreads();  // previous tile fully consumed
#pragma unroll
        for (int i = 0; i < 2; ++i) {
            int o  = (((i << 2) + wave) << 10);     // wave-uniform byte offset in tile
            int ob = o + (lane << 4);               // this lane's byte
            int row = ob >> 6, colb = ob & 63;      // 64B per row (32 bf16 = BK)
            g2l16((const char*)A + ((size_t)(m0 + row) * Ks + k0) * 2 + colb, (char*)As + o);
            g2l16((const char*)W + ((size_t)(n0 + row) * Ks + k0) * 2 + colb, (char*)Ws + o);
        }
        __syncthreads();  // compiler drains vmcnt before s_barrier

        bfx8 af[4], wf[4];
#pragma unroll
        for (int mt = 0; mt < 4; ++mt)
            af[mt] = *(const bfx8*)&As[((wm + (mt << 4) + r15) << 5) + (q << 3)];
#pragma unroll
        for (int nt = 0; nt < 4; ++nt)
            wf[nt] = *(const bfx8*)&Ws[((wn + (nt << 4) + r15) << 5) + (q << 3)];
#pragma unroll
        for (int mt = 0; mt < 4; ++mt)
#pragma unroll
            for (int nt = 0; nt < 4; ++nt)
                acc[mt][nt] = __builtin_amdgcn_mfma_f32_16x16x32_bf16(af[mt], wf[nt], acc[mt][nt], 0, 0, 0);
    }

    // epilogue: D col = lane&15, row = (lane>>4)*4 + reg  [m89-verified]
#pragma unroll
    for (int nt = 0; nt < 4; ++nt) {
        int col = n0 + wn + (nt << 4) + r15;
        float bv = bias[col];
#pragma unroll
        for (int mt = 0; mt < 4; ++mt) {
#pragma unroll
            for (int i = 0; i < 4; ++i) {
                int rrow = m0 + wm + (mt << 4) + (q << 2) + i;
                float v = acc[mt][nt][i] + bv;
                if (OUTBF16) ((__bf16*)C)[(size_t)rrow * N + col] = (__bf16)v;
                else         ((float*)C)[(size_t)rrow * N + col]  = v;
            }
        }
    }
}

// ---------------- GRU recurrence: persistent cooperative kernel ----------------
// 256 blocks = 4 batch-quarters (bb) x 64 H-slices (bj, 16 units each), 256 threads.
// Per block LDS: w_hh slice 48 rows x 1024 (row pad +8 bf16 for bank spread) = 99KB,
// h stage 16 x 1024 (+pad) = 33KB, gh exchange 3KB.  Total ~135KB < 160KB.
__device__ __forceinline__ float sigm(float x) { return 1.f / (1.f + __expf(-x)); }
__device__ __forceinline__ float tanh_f(float x) { float e = __expf(2.f * x); return 1.f - 2.f / (e + 1.f); }

#define RP 1032  // padded row stride in bf16 units (2064 B)

__global__ __launch_bounds__(256, 1)
void rnn_kernel(const float* __restrict__ gx, const int* __restrict__ lens,
                const __bf16* __restrict__ whhb, const float* __restrict__ b_hh,
                __bf16* __restrict__ hbuf,   // [2][64][1024] bf16, zeroed
                float* __restrict__ out,     // B*T*H then B*H
                unsigned int* __restrict__ cnt)  // zeroed
{
    __shared__ __bf16 whh_s[48 * RP];
    __shared__ __bf16 hs[16 * RP];
    __shared__ float  ghs[3 * 256];

    const int tid  = threadIdx.x;
    const int wave = tid >> 6, lane = tid & 63;
    const int q = lane >> 4, r15 = lane & 15;
    const int bb = blockIdx.x >> 6, bj = blockIdx.x & 63;

    // preload w_hh slice: LDS row (g*16+jj) <- w_hh row (g*1024 + bj*16 + jj)
    for (int i = tid; i < 6144; i += 256) {
        int row = i >> 7, c = i & 127;
        int g = row >> 4, jj = row & 15;
        uint4 v = *(const uint4*)(whhb + ((size_t)((g << 10) + (bj << 4) + jj) << 10) + (c << 3));
        *(uint4*)&whh_s[row * RP + (c << 3)] = v;
    }

    const int m_ = tid >> 4, jj_ = tid & 15;
    const int bglob = (bb << 4) + m_;
    const int jglob = (bj << 4) + jj_;
    const float bhr = b_hh[jglob], bhz = b_hh[1024 + jglob], bhn = b_hh[2048 + jglob];
    const int mylen = lens[bglob];
    const float* gxbase = gx + (size_t)bglob * 256 * 3072 + jglob;
    float hstate = 0.f;
    __syncthreads();

    for (int t = 0; t < 256; ++t) {
        // prefetch gx early (independent of h) to hide HBM latency behind MFMA
        const float* gp = gxbase + (size_t)t * 3072;
        float gir = gp[0], giz = gp[1024], gin = gp[2048];

        // stage this batch-quarter's h (bf16) into LDS
        const __bf16* hsrc = hbuf + ((size_t)(t & 1) << 16) + (bb << 14);
        for (int i = tid; i < 2048; i += 256) {
            int m = i >> 7, c = i & 127;
            uint4 v = *(const uint4*)(hsrc + (m << 10) + (c << 3));
            *(uint4*)&hs[m * RP + (c << 3)] = v;
        }
        __syncthreads();

        // waves 0..2: gate g = wave; D[16 batch][16 units] = h(16x1024) @ w_hh_slice^T
        if (wave < 3) {
            f32x4 acc = {0.f, 0.f, 0.f, 0.f};
            const __bf16* wrow = &whh_s[(wave * 16 + r15) * RP];  // B: n = lane&15
            const __bf16* hrow = &hs[r15 * RP];                   // A: m = lane&15
#pragma unroll
            for (int kk = 0; kk < 32; ++kk) {
                bfx8 a = *(const bfx8*)(hrow + (kk << 5) + (q << 3));
                bfx8 b = *(const bfx8*)(wrow + (kk << 5) + (q << 3));
                acc = __builtin_amdgcn_mfma_f32_16x16x32_bf16(a, b, acc, 0, 0, 0);
            }
#pragma unroll
            for (int i2 = 0; i2 < 4; ++i2)
                ghs[wave * 256 + (((q << 2) + i2) << 4) + r15] = acc[i2];
        }
        __syncthreads();

        // gates: thread <-> (batch m_, unit jj_)
        float ghr = ghs[tid] + bhr;
        float ghz = ghs[256 + tid] + bhz;
        float ghn = ghs[512 + tid] + bhn;
        float rg = sigm(gir + ghr);
        float zg = sigm(giz + ghz);
        float ng = tanh_f(gin + rg * ghn);
        float hnew = (1.f - zg) * ng + zg * hstate;
        bool mk = t < mylen;
        hstate = mk ? hnew : hstate;
        float y = mk ? hnew : 0.f;
        out[(size_t)(bglob * 256 + t) * 1024 + jglob] = y;
        if (t == 255) out[(size_t)64 * 256 * 1024 + ((size_t)bglob << 10) + jglob] = y;
        hbuf[((size_t)((t + 1) & 1) << 16) + ((size_t)bglob << 10) + jglob] = (__bf16)hstate;

        if (t < 255) {
            __syncthreads();  // drains vmcnt: all block's hbuf stores in L2
            if (tid == 0) {
                // release: wb L2 (cross-XCD visibility), monotone counter => no reset races
                __hip_atomic_fetch_add(cnt, 1u, __ATOMIC_RELEASE, __HIP_MEMORY_SCOPE_AGENT);
                unsigned int target = 256u * (unsigned)(t + 1);
                while (__hip_atomic_load(cnt, __ATOMIC_ACQUIRE, __HIP_MEMORY_SCOPE_AGENT) < target)
                    __builtin_amdgcn_s_sleep(1);
                // acquire: inv L1/L2 so next stage reads fresh h
            }
            __syncthreads();
        }
    }
}

// ---------------- launch ----------------
extern "C" void kernel_launch(void* const* d_in, const int* in_sizes, int n_in,
                              void* d_out, int out_size, void* d_ws, size_t ws_size,
                              hipStream_t stream) {
    const float* input = (const float*)d_in[0];
    const int*   lens  = (const int*)d_in[1];
    const float* W_p   = (const float*)d_in[2];
    const float* b_p   = (const float*)d_in[3];
    const float* w_ih  = (const float*)d_in[4];
    const float* w_hh  = (const float*)d_in[5];
    const float* b_ih  = (const float*)d_in[6];
    const float* b_hh  = (const float*)d_in[7];
    float* out = (float*)d_out;
    char* ws = (char*)d_ws;

    // workspace layout (bytes): total ~319 MB
    __bf16* Xb   = (__bf16*)(ws + 0);            // 67,108,864
    __bf16* Wpb  = (__bf16*)(ws + 67108864);     //  4,194,304
    __bf16* wihb = (__bf16*)(ws + 71303168);     //  6,291,456
    __bf16* whhb = (__bf16*)(ws + 77594624);     //  6,291,456
    __bf16* embb = (__bf16*)(ws + 83886080);     // 33,554,432
    float*  gx   = (float*) (ws + 117440512);    // 201,326,592
    __bf16* hbuf = (__bf16*)(ws + 318767104);    //    262,144 (double-buffered h)
    unsigned int* cnt = (unsigned int*)(ws + 319029248);

    // zero h state + barrier counter (d_ws is poisoned 0xAA before every launch)
    hipMemsetAsync(ws + 318767104, 0, 262144 + 256, stream);

    cvt_bf16<<<4096, 256, 0, stream>>>(input, Xb, 33554432 / 8);
    cvt_bf16<<<1024, 256, 0, stream>>>(W_p,  Wpb, 2097152 / 8);
    cvt_bf16<<<1536, 256, 0, stream>>>(w_ih, wihb, 3145728 / 8);
    cvt_bf16<<<1536, 256, 0, stream>>>(w_hh, whhb, 3145728 / 8);

    // emb = X @ W_p^T + b_p  (bf16 out), M=16384 N=1024 K=2048
    gemm_bt<true><<<dim3(8, 128), 256, 0, stream>>>(Xb, Wpb, b_p, embb, 16384, 1024, 2048);
    // gx = emb @ w_ih^T + b_ih (f32 out), M=16384 N=3072 K=1024
    gemm_bt<false><<<dim3(24, 128), 256, 0, stream>>>(embb, wihb, b_ih, gx, 16384, 3072, 1024);

    // recurrence: 256 blocks (all CUs, 1 block/CU, co-resident), 256 steps
    rnn_kernel<<<256, 256, 0, stream>>>(gx, lens, whhb, b_hh, hbuf, out, cnt);
}

// Round 2
// 3288.792 us; speedup vs baseline: 1.2225x; 1.2225x over previous
//
#include <hip/hip_runtime.h>
#include <stdint.h>

// Problem: B=64, T=256, F_IN=2048, H=1024, 3H=3072, M=B*T=16384.
// d_in: 0 input_var f32[64,256,2048], 1 input_lengths i32[64], 2 W_p f32[1024,2048],
//       3 b_p f32[1024], 4 w_ih f32[3072,1024], 5 w_hh f32[3072,1024],
//       6 b_ih f32[3072], 7 b_hh f32[3072]
// d_out: output f32[64,256,1024] then hidden f32[64,1024]

typedef __bf16 bfx8 __attribute__((ext_vector_type(8)));
typedef float  f32x4 __attribute__((ext_vector_type(4)));

// ---------------- fp32 -> bf16 conversion (8 elems/thread) ----------------
__global__ void cvt_bf16(const float* __restrict__ in, __bf16* __restrict__ out, int n8) {
    for (int i = blockIdx.x * blockDim.x + threadIdx.x; i < n8; i += gridDim.x * blockDim.x) {
        float4 a = ((const float4*)in)[2 * i];
        float4 b = ((const float4*)in)[2 * i + 1];
        union { __bf16 h[8]; uint4 v; } u;
        u.h[0] = (__bf16)a.x; u.h[1] = (__bf16)a.y; u.h[2] = (__bf16)a.z; u.h[3] = (__bf16)a.w;
        u.h[4] = (__bf16)b.x; u.h[5] = (__bf16)b.y; u.h[6] = (__bf16)b.z; u.h[7] = (__bf16)b.w;
        ((uint4*)out)[i] = u.v;
    }
}

// ---------------- async global->LDS 16B ----------------
__device__ __forceinline__ void g2l16(const void* g, void* l) {
    __builtin_amdgcn_global_load_lds(
        (__attribute__((address_space(1))) void*)g,
        (__attribute__((address_space(3))) void*)l,
        16, 0, 0);
}

// ---------------- m97-style bf16 GEMM: C[M][N] = A[M][K] * W[N][K]^T + bias ----------------
// 128x128 tile, BK=32, 256 threads = 4 waves in 2x2, each wave 64x64 (4x4 MFMA tiles).
template <bool OUTBF16>
__global__ __launch_bounds__(256)
void gemm_bt(const __bf16* __restrict__ A, const __bf16* __restrict__ W,
             const float* __restrict__ bias, void* __restrict__ C,
             int M, int N, int K)
{
    __shared__ __bf16 As[128 * 32];
    __shared__ __bf16 Ws[128 * 32];
    const int tid  = threadIdx.x;
    const int wave = tid >> 6, lane = tid & 63;
    const int q = lane >> 4, r15 = lane & 15;
    const int n0 = blockIdx.x << 7, m0 = blockIdx.y << 7;
    const int wm = (wave >> 1) << 6, wn = (wave & 1) << 6;
    const size_t Ks = (size_t)K;
    f32x4 acc[4][4] = {};

    for (int k0 = 0; k0 < K; k0 += 32) {
        __syncthreads();  // previous tile fully consumed
#pragma unroll
        for (int i = 0; i < 2; ++i) {
            int o  = (((i << 2) + wave) << 10);     // wave-uniform byte offset in tile
            int ob = o + (lane << 4);               // this lane's byte
            int row = ob >> 6, colb = ob & 63;      // 64B per row (32 bf16 = BK)
            g2l16((const char*)A + ((size_t)(m0 + row) * Ks + k0) * 2 + colb, (char*)As + o);
            g2l16((const char*)W + ((size_t)(n0 + row) * Ks + k0) * 2 + colb, (char*)Ws + o);
        }
        __syncthreads();  // compiler drains vmcnt before s_barrier

        bfx8 af[4], wf[4];
#pragma unroll
        for (int mt = 0; mt < 4; ++mt)
            af[mt] = *(const bfx8*)&As[((wm + (mt << 4) + r15) << 5) + (q << 3)];
#pragma unroll
        for (int nt = 0; nt < 4; ++nt)
            wf[nt] = *(const bfx8*)&Ws[((wn + (nt << 4) + r15) << 5) + (q << 3)];
#pragma unroll
        for (int mt = 0; mt < 4; ++mt)
#pragma unroll
            for (int nt = 0; nt < 4; ++nt)
                acc[mt][nt] = __builtin_amdgcn_mfma_f32_16x16x32_bf16(af[mt], wf[nt], acc[mt][nt], 0, 0, 0);
    }

    // epilogue: D col = lane&15, row = (lane>>4)*4 + reg  [m89-verified]
#pragma unroll
    for (int nt = 0; nt < 4; ++nt) {
        int col = n0 + wn + (nt << 4) + r15;
        float bv = bias[col];
#pragma unroll
        for (int mt = 0; mt < 4; ++mt) {
#pragma unroll
            for (int i = 0; i < 4; ++i) {
                int rrow = m0 + wm + (mt << 4) + (q << 2) + i;
                float v = acc[mt][nt][i] + bv;
                if (OUTBF16) ((__bf16*)C)[(size_t)rrow * N + col] = (__bf16)v;
                else         ((float*)C)[(size_t)rrow * N + col]  = v;
            }
        }
    }
}

// ---------------- GRU recurrence: persistent cooperative kernel ----------------
// 256 blocks = 4 batch-quarters (bb) x 64 H-slices (bj, 16 units each), 256 threads.
// Per block LDS: w_hh slice 48 rows x 1024 (row pad +8 bf16) = 99KB,
// h stage 16 x 1024 (+pad) = 33KB, gh exchange 3KB.  Total ~135KB < 160KB.
//
// Barrier redesign (R2): R1's central counter cost ~12us/step — 256 serialized
// RMWs on one line + an L2-invalidating ACQUIRE load per poll iteration (the
// inv thrashed the gx stream: FETCH_SIZE 331MB vs 210MB ideal). Now: one
// release-store per block to its OWN 64B-padded flag (publishes h via wbL2),
// wave-0 lanes poll the 64 producer flags of their batch group in PARALLEL
// with RELAXED agent loads (no inv), then ONE acquire fence per step.
__device__ __forceinline__ float sigm(float x) { return 1.f / (1.f + __expf(-x)); }
__device__ __forceinline__ float tanh_f(float x) { float e = __expf(2.f * x); return 1.f - 2.f / (e + 1.f); }

#define RP 1032  // padded row stride in bf16 units (2064 B, 16B-aligned, 2-way-bank = free)

__global__ __launch_bounds__(256, 1)
void rnn_kernel(const float* __restrict__ gx, const int* __restrict__ lens,
                const __bf16* __restrict__ whhb, const float* __restrict__ b_hh,
                __bf16* __restrict__ hbuf,       // [2][64][1024] bf16, zeroed
                float* __restrict__ out,         // B*T*H then B*H
                unsigned int* __restrict__ flags) // 256 flags, 64B apart, zeroed
{
    __shared__ __bf16 whh_s[48 * RP];
    __shared__ __bf16 hs[16 * RP];
    __shared__ float  ghs[3 * 256];

    const int tid  = threadIdx.x;
    const int wave = tid >> 6, lane = tid & 63;
    const int q = lane >> 4, r15 = lane & 15;
    const int bb = blockIdx.x >> 6, bj = blockIdx.x & 63;

    // preload w_hh slice: LDS row (g*16+jj) <- w_hh row (g*1024 + bj*16 + jj)
    for (int i = tid; i < 6144; i += 256) {
        int row = i >> 7, c = i & 127;
        int g = row >> 4, jj = row & 15;
        uint4 v = *(const uint4*)(whhb + ((size_t)((g << 10) + (bj << 4) + jj) << 10) + (c << 3));
        *(uint4*)&whh_s[row * RP + (c << 3)] = v;
    }

    const int m_ = tid >> 4, jj_ = tid & 15;
    const int bglob = (bb << 4) + m_;
    const int jglob = (bj << 4) + jj_;
    const float bhr = b_hh[jglob], bhz = b_hh[1024 + jglob], bhn = b_hh[2048 + jglob];
    const int mylen = lens[bglob];
    const float* gxbase = gx + (size_t)bglob * 256 * 3072 + jglob;
    float hstate = 0.f;
    __syncthreads();

    for (int t = 0; t < 256; ++t) {
        // gx load issued at step top: ~900ns HBM latency hides under staging+MFMA
        const float* gp = gxbase + (size_t)t * 3072;
        float gir = gp[0], giz = gp[1024], gin = gp[2048];

        // stage this batch-quarter's h (bf16) into LDS
        const __bf16* hsrc = hbuf + ((size_t)(t & 1) << 16) + (bb << 14);
        for (int i = tid; i < 2048; i += 256) {
            int m = i >> 7, c = i & 127;
            uint4 v = *(const uint4*)(hsrc + (m << 10) + (c << 3));
            *(uint4*)&hs[m * RP + (c << 3)] = v;
        }
        __syncthreads();

        // waves 0..2: gate g = wave; D[16 batch][16 units] = h(16x1024) @ w_hh_slice^T
        if (wave < 3) {
            f32x4 acc = {0.f, 0.f, 0.f, 0.f};
            const __bf16* wrow = &whh_s[(wave * 16 + r15) * RP];  // B: n = lane&15
            const __bf16* hrow = &hs[r15 * RP];                   // A: m = lane&15
#pragma unroll
            for (int kk = 0; kk < 32; ++kk) {
                bfx8 a = *(const bfx8*)(hrow + (kk << 5) + (q << 3));
                bfx8 b = *(const bfx8*)(wrow + (kk << 5) + (q << 3));
                acc = __builtin_amdgcn_mfma_f32_16x16x32_bf16(a, b, acc, 0, 0, 0);
            }
#pragma unroll
            for (int i2 = 0; i2 < 4; ++i2)
                ghs[wave * 256 + (((q << 2) + i2) << 4) + r15] = acc[i2];
        }
        __syncthreads();

        // gates: thread <-> (batch m_, unit jj_)
        float ghr = ghs[tid] + bhr;
        float ghz = ghs[256 + tid] + bhz;
        float ghn = ghs[512 + tid] + bhn;
        float rg = sigm(gir + ghr);
        float zg = sigm(giz + ghz);
        float ng = tanh_f(gin + rg * ghn);
        float hnew = (1.f - zg) * ng + zg * hstate;
        bool mk = t < mylen;
        hstate = mk ? hnew : hstate;
        float y = mk ? hnew : 0.f;
        out[(size_t)(bglob * 256 + t) * 1024 + jglob] = y;
        if (t == 255) out[(size_t)64 * 256 * 1024 + ((size_t)bglob << 10) + jglob] = y;
        hbuf[((size_t)((t + 1) & 1) << 16) + ((size_t)bglob << 10) + jglob] = (__bf16)hstate;

        if (t < 255) {
            __syncthreads();  // drains vmcnt: all block's hbuf stores in L2
            if (tid == 0) {
                // arrival: ONE release store to our own padded flag line.
                // Release wbL2 publishes our h chunk to LLC (cross-XCD).
                __hip_atomic_store(&flags[blockIdx.x << 4], (unsigned)(t + 1),
                                   __ATOMIC_RELEASE, __HIP_MEMORY_SCOPE_AGENT);
            }
            if (wave == 0) {
                // wait: lane l polls producer (bb,l)'s flag — 64 parallel RELAXED
                // loads (no L2 inv per poll); exec-mask loop exits when all 64 done.
                const unsigned* fp = &flags[((bb << 6) + lane) << 4];
                unsigned tgt = (unsigned)(t + 1);
                while (__hip_atomic_load(fp, __ATOMIC_RELAXED, __HIP_MEMORY_SCOPE_AGENT) < tgt)
                    __builtin_amdgcn_s_sleep(1);
                // single acquire: invalidate stale L1/L2 so staged h reads are fresh
                __builtin_amdgcn_fence(__ATOMIC_ACQUIRE, "agent");
            }
            __syncthreads();
        }
    }
}

// ---------------- launch ----------------
extern "C" void kernel_launch(void* const* d_in, const int* in_sizes, int n_in,
                              void* d_out, int out_size, void* d_ws, size_t ws_size,
                              hipStream_t stream) {
    const float* input = (const float*)d_in[0];
    const int*   lens  = (const int*)d_in[1];
    const float* W_p   = (const float*)d_in[2];
    const float* b_p   = (const float*)d_in[3];
    const float* w_ih  = (const float*)d_in[4];
    const float* w_hh  = (const float*)d_in[5];
    const float* b_ih  = (const float*)d_in[6];
    const float* b_hh  = (const float*)d_in[7];
    float* out = (float*)d_out;
    char* ws = (char*)d_ws;

    // workspace layout (bytes): total ~319 MB
    __bf16* Xb   = (__bf16*)(ws + 0);            // 67,108,864
    __bf16* Wpb  = (__bf16*)(ws + 67108864);     //  4,194,304
    __bf16* wihb = (__bf16*)(ws + 71303168);     //  6,291,456
    __bf16* whhb = (__bf16*)(ws + 77594624);     //  6,291,456
    __bf16* embb = (__bf16*)(ws + 83886080);     // 33,554,432
    float*  gx   = (float*) (ws + 117440512);    // 201,326,592
    __bf16* hbuf = (__bf16*)(ws + 318767104);    //    262,144 (double-buffered h)
    unsigned int* flags = (unsigned int*)(ws + 319029248);  // 256 x 64B = 16,384

    // zero h state + flags (d_ws is poisoned 0xAA before every launch)
    hipMemsetAsync(ws + 318767104, 0, 262144 + 16384, stream);

    cvt_bf16<<<4096, 256, 0, stream>>>(input, Xb, 33554432 / 8);
    cvt_bf16<<<1024, 256, 0, stream>>>(W_p,  Wpb, 2097152 / 8);
    cvt_bf16<<<1536, 256, 0, stream>>>(w_ih, wihb, 3145728 / 8);
    cvt_bf16<<<1536, 256, 0, stream>>>(w_hh, whhb, 3145728 / 8);

    // emb = X @ W_p^T + b_p  (bf16 out), M=16384 N=1024 K=2048
    gemm_bt<true><<<dim3(8, 128), 256, 0, stream>>>(Xb, Wpb, b_p, embb, 16384, 1024, 2048);
    // gx = emb @ w_ih^T + b_ih (f32 out), M=16384 N=3072 K=1024
    gemm_bt<false><<<dim3(24, 128), 256, 0, stream>>>(embb, wihb, b_ih, gx, 16384, 3072, 1024);

    // recurrence: 256 blocks (1 block/CU, co-resident), 256 steps
    rnn_kernel<<<256, 256, 0, stream>>>(gx, lens, whhb, b_hh, hbuf, out, flags);
}

// Round 3
// 3035.634 us; speedup vs baseline: 1.3244x; 1.0834x over previous
//
#include <hip/hip_runtime.h>
#include <stdint.h>

// Problem: B=64, T=256, F_IN=2048, H=1024, 3H=3072, M=B*T=16384.
// d_out: output f32[64,256,1024] then hidden f32[64,1024]

typedef __bf16 bfx8 __attribute__((ext_vector_type(8)));
typedef float  f32x4 __attribute__((ext_vector_type(4)));

// ---------------- fp32 -> bf16 conversion (8 elems/thread) ----------------
__global__ void cvt_bf16(const float* __restrict__ in, __bf16* __restrict__ out, int n8) {
    for (int i = blockIdx.x * blockDim.x + threadIdx.x; i < n8; i += gridDim.x * blockDim.x) {
        float4 a = ((const float4*)in)[2 * i];
        float4 b = ((const float4*)in)[2 * i + 1];
        union { __bf16 h[8]; uint4 v; } u;
        u.h[0] = (__bf16)a.x; u.h[1] = (__bf16)a.y; u.h[2] = (__bf16)a.z; u.h[3] = (__bf16)a.w;
        u.h[4] = (__bf16)b.x; u.h[5] = (__bf16)b.y; u.h[6] = (__bf16)b.z; u.h[7] = (__bf16)b.w;
        ((uint4*)out)[i] = u.v;
    }
}

// ---------------- async global->LDS 16B ----------------
__device__ __forceinline__ void g2l16(const void* g, void* l) {
    __builtin_amdgcn_global_load_lds(
        (__attribute__((address_space(1))) void*)g,
        (__attribute__((address_space(3))) void*)l,
        16, 0, 0);
}

// ---------------- m97-style bf16 GEMM: C[M][N] = A[M][K] * W[N][K]^T + bias ----------------
template <bool OUTBF16>
__global__ __launch_bounds__(256)
void gemm_bt(const __bf16* __restrict__ A, const __bf16* __restrict__ W,
             const float* __restrict__ bias, void* __restrict__ C,
             int M, int N, int K)
{
    __shared__ __bf16 As[128 * 32];
    __shared__ __bf16 Ws[128 * 32];
    const int tid  = threadIdx.x;
    const int wave = tid >> 6, lane = tid & 63;
    const int q = lane >> 4, r15 = lane & 15;
    const int n0 = blockIdx.x << 7, m0 = blockIdx.y << 7;
    const int wm = (wave >> 1) << 6, wn = (wave & 1) << 6;
    const size_t Ks = (size_t)K;
    f32x4 acc[4][4] = {};

    for (int k0 = 0; k0 < K; k0 += 32) {
        __syncthreads();
#pragma unroll
        for (int i = 0; i < 2; ++i) {
            int o  = (((i << 2) + wave) << 10);
            int ob = o + (lane << 4);
            int row = ob >> 6, colb = ob & 63;
            g2l16((const char*)A + ((size_t)(m0 + row) * Ks + k0) * 2 + colb, (char*)As + o);
            g2l16((const char*)W + ((size_t)(n0 + row) * Ks + k0) * 2 + colb, (char*)Ws + o);
        }
        __syncthreads();

        bfx8 af[4], wf[4];
#pragma unroll
        for (int mt = 0; mt < 4; ++mt)
            af[mt] = *(const bfx8*)&As[((wm + (mt << 4) + r15) << 5) + (q << 3)];
#pragma unroll
        for (int nt = 0; nt < 4; ++nt)
            wf[nt] = *(const bfx8*)&Ws[((wn + (nt << 4) + r15) << 5) + (q << 3)];
#pragma unroll
        for (int mt = 0; mt < 4; ++mt)
#pragma unroll
            for (int nt = 0; nt < 4; ++nt)
                acc[mt][nt] = __builtin_amdgcn_mfma_f32_16x16x32_bf16(af[mt], wf[nt], acc[mt][nt], 0, 0, 0);
    }

#pragma unroll
    for (int nt = 0; nt < 4; ++nt) {
        int col = n0 + wn + (nt << 4) + r15;
        float bv = bias[col];
#pragma unroll
        for (int mt = 0; mt < 4; ++mt) {
#pragma unroll
            for (int i = 0; i < 4; ++i) {
                int rrow = m0 + wm + (mt << 4) + (q << 2) + i;
                float v = acc[mt][nt][i] + bv;
                if (OUTBF16) ((__bf16*)C)[(size_t)rrow * N + col] = (__bf16)v;
                else         ((float*)C)[(size_t)rrow * N + col]  = v;
            }
        }
    }
}

// ---------------- GRU recurrence: persistent cooperative kernel ----------------
// 256 blocks = 4 batch-groups (bb, 16 batches) x 64 H-slices (bj, 16 units).
// R3: FENCE-FREE sync. R2's remaining 10.9us/step was cache maintenance:
// agent RELEASE store => per-XCD L2 writeback walk, agent ACQUIRE fence =>
// L1+L2 invalidate walk — 256 of each per step, serialized at the TCCs, and
// the invs thrashed the gx stream (FETCH 360MB vs 210MB ideal). Now hbuf
// itself is accessed with RELAXED agent-scope 4B atomics (write-through /
// read-through to LLC, no cache ops). Ordering: __syncthreads drains vmcnt
// (stores acked at coherence point) before the relaxed flag store; consumer
// poll -> h reads ordered by LLC serialization + compiler barrier.
// Block mapping is XCD-aware: group bb = (blockIdx&7)>>1 lives on 2 XCDs.
__device__ __forceinline__ float sigm(float x) { return 1.f / (1.f + __expf(-x)); }
__device__ __forceinline__ float tanh_f(float x) { float e = __expf(2.f * x); return 1.f - 2.f / (e + 1.f); }

#define RP 1032  // padded LDS row stride in bf16 (2064 B)

__global__ __launch_bounds__(256, 1)
void rnn_kernel(const float* __restrict__ gx, const int* __restrict__ lens,
                const __bf16* __restrict__ whhb, const float* __restrict__ b_hh,
                unsigned* __restrict__ hbuf,     // [2][64][512] u32 (=1024 bf16), zeroed
                float* __restrict__ out,         // B*T*H then B*H
                unsigned* __restrict__ flags)    // 256 flags, 64B apart, zeroed
{
    __shared__ __bf16 whh_s[48 * RP];
    __shared__ __bf16 hs[16 * RP];
    __shared__ float  ghs[3 * 256];
    __shared__ unsigned hx[128];                 // packed h for publication

    const int tid  = threadIdx.x;
    const int wave = tid >> 6, lane = tid & 63;
    const int q = lane >> 4, r15 = lane & 15;
    const int bb = (blockIdx.x & 7) >> 1;                         // batch group (2 XCDs)
    const int bj = ((blockIdx.x >> 3) << 1) | (blockIdx.x & 1);   // unit slice 0..63

    // preload w_hh slice: LDS row (g*16+jj) <- w_hh row (g*1024 + bj*16 + jj)
    for (int i = tid; i < 6144; i += 256) {
        int row = i >> 7, c = i & 127;
        int g = row >> 4, jj = row & 15;
        uint4 v = *(const uint4*)(whhb + ((size_t)((g << 10) + (bj << 4) + jj) << 10) + (c << 3));
        *(uint4*)&whh_s[row * RP + (c << 3)] = v;
    }

    const int m_ = tid >> 4, jj_ = tid & 15;
    const int bglob = (bb << 4) + m_;
    const int jglob = (bj << 4) + jj_;
    const float bhr = b_hh[jglob], bhz = b_hh[1024 + jglob], bhn = b_hh[2048 + jglob];
    const int mylen = lens[bglob];
    const float* gp = gx + (size_t)bglob * 256 * 3072 + jglob;
    float gir = gp[0], giz = gp[1024], gin = gp[2048];   // gx for t=0
    float hstate = 0.f;
    __syncthreads();

    for (int t = 0; t < 256; ++t) {
        // ---- stage h_t (32KB) via device-coherent 4B loads: bypass stale L1/L2,
        //      so NO acquire fence / L2 invalidate is ever needed ----
        const unsigned hb = ((unsigned)(t & 1) << 15) + (unsigned)(bb << 13);
#pragma unroll 8
        for (int i = tid; i < 8192; i += 256) {
            unsigned v = __hip_atomic_load(hbuf + hb + i, __ATOMIC_RELAXED, __HIP_MEMORY_SCOPE_AGENT);
            int m = i >> 9, c = i & 511;
            *(unsigned*)&hs[m * RP + (c << 1)] = v;
        }
        __syncthreads();

        // waves 0..2: gate g = wave; D[16 batch][16 units] = h(16x1024) @ w_hh^T
        if (wave < 3) {
            f32x4 acc = {0.f, 0.f, 0.f, 0.f};
            const __bf16* wrow = &whh_s[(wave * 16 + r15) * RP];
            const __bf16* hrow = &hs[r15 * RP];
#pragma unroll
            for (int kk = 0; kk < 32; ++kk) {
                bfx8 a = *(const bfx8*)(hrow + (kk << 5) + (q << 3));
                bfx8 b = *(const bfx8*)(wrow + (kk << 5) + (q << 3));
                acc = __builtin_amdgcn_mfma_f32_16x16x32_bf16(a, b, acc, 0, 0, 0);
            }
#pragma unroll
            for (int i2 = 0; i2 < 4; ++i2)
                ghs[wave * 256 + (((q << 2) + i2) << 4) + r15] = acc[i2];
        }
        __syncthreads();

        // gates: thread <-> (batch m_, unit jj_)
        float ghr = ghs[tid] + bhr;
        float ghz = ghs[256 + tid] + bhz;
        float ghn = ghs[512 + tid] + bhn;
        float rg = sigm(gir + ghr);
        float zg = sigm(giz + ghz);
        float ng = tanh_f(gin + rg * ghn);
        float hnew = (1.f - zg) * ng + zg * hstate;
        bool mk = t < mylen;
        hstate = mk ? hnew : hstate;
        float y = mk ? hnew : 0.f;
        out[(size_t)(bglob * 256 + t) * 1024 + jglob] = y;
        if (t == 255) out[(size_t)(64 * 256) * 1024 + ((size_t)bglob << 10) + jglob] = y;

        if (t < 255) {
            // pack h into LDS, prefetch next gx BEFORE the sync round
            ((__bf16*)hx)[(m_ << 4) + jj_] = (__bf16)hstate;
            gp += 3072;
            gir = gp[0]; giz = gp[1024]; gin = gp[2048];
            __syncthreads();
            if (tid < 128) {
                // publish 512B of h: device-coherent 4B stores (write-through, no wbL2)
                unsigned nb = ((unsigned)((t + 1) & 1) << 15) + (unsigned)(bb << 13)
                            + ((tid >> 3) << 9) + (bj << 3) + (tid & 7);
                __hip_atomic_store(hbuf + nb, hx[tid], __ATOMIC_RELAXED, __HIP_MEMORY_SCOPE_AGENT);
            }
            __syncthreads();  // vmcnt(0) drain in every wave => h-stores at LLC
            if (tid == 0)
                __hip_atomic_store(&flags[blockIdx.x << 4], (unsigned)(t + 1),
                                   __ATOMIC_RELAXED, __HIP_MEMORY_SCOPE_AGENT);
            if (wave == 0) {
                // lane l polls producer ((l>>1)*8 + 2bb + (l&1)) — the 64 blocks of group bb
                int pid = ((lane >> 1) << 3) + (bb << 1) + (lane & 1);
                const unsigned* fp = &flags[pid << 4];
                unsigned tgt = (unsigned)(t + 1);
                while (__hip_atomic_load(fp, __ATOMIC_RELAXED, __HIP_MEMORY_SCOPE_AGENT) < tgt)
                    __builtin_amdgcn_s_sleep(1);
                asm volatile("" ::: "memory");  // keep h reads after the poll
            }
            __syncthreads();
        }
    }
}

// ---------------- launch ----------------
extern "C" void kernel_launch(void* const* d_in, const int* in_sizes, int n_in,
                              void* d_out, int out_size, void* d_ws, size_t ws_size,
                              hipStream_t stream) {
    const float* input = (const float*)d_in[0];
    const int*   lens  = (const int*)d_in[1];
    const float* W_p   = (const float*)d_in[2];
    const float* b_p   = (const float*)d_in[3];
    const float* w_ih  = (const float*)d_in[4];
    const float* w_hh  = (const float*)d_in[5];
    const float* b_ih  = (const float*)d_in[6];
    const float* b_hh  = (const float*)d_in[7];
    float* out = (float*)d_out;
    char* ws = (char*)d_ws;

    // workspace layout (bytes): total ~319 MB
    __bf16* Xb   = (__bf16*)(ws + 0);            // 67,108,864
    __bf16* Wpb  = (__bf16*)(ws + 67108864);     //  4,194,304
    __bf16* wihb = (__bf16*)(ws + 71303168);     //  6,291,456
    __bf16* whhb = (__bf16*)(ws + 77594624);     //  6,291,456
    __bf16* embb = (__bf16*)(ws + 83886080);     // 33,554,432
    float*  gx   = (float*) (ws + 117440512);    // 201,326,592
    unsigned* hbuf = (unsigned*)(ws + 318767104);   // 262,144 (double-buffered h)
    unsigned* flags = (unsigned*)(ws + 319029248);  // 256 x 64B = 16,384

    // zero h state + flags (d_ws is poisoned 0xAA before every launch)
    hipMemsetAsync(ws + 318767104, 0, 262144 + 16384, stream);

    cvt_bf16<<<4096, 256, 0, stream>>>(input, Xb, 33554432 / 8);
    cvt_bf16<<<1024, 256, 0, stream>>>(W_p,  Wpb, 2097152 / 8);
    cvt_bf16<<<1536, 256, 0, stream>>>(w_ih, wihb, 3145728 / 8);
    cvt_bf16<<<1536, 256, 0, stream>>>(w_hh, whhb, 3145728 / 8);

    // emb = X @ W_p^T + b_p  (bf16 out), M=16384 N=1024 K=2048
    gemm_bt<true><<<dim3(8, 128), 256, 0, stream>>>(Xb, Wpb, b_p, embb, 16384, 1024, 2048);
    // gx = emb @ w_ih^T + b_ih (f32 out), M=16384 N=3072 K=1024
    gemm_bt<false><<<dim3(24, 128), 256, 0, stream>>>(embb, wihb, b_ih, gx, 16384, 3072, 1024);

    // recurrence: 256 blocks (1 block/CU, co-resident), 256 steps
    rnn_kernel<<<256, 256, 0, stream>>>(gx, lens, whhb, b_hh, hbuf, out, flags);
}

// Round 5
// 1380.217 us; speedup vs baseline: 2.9129x; 2.1994x over previous
//
#include <hip/hip_runtime.h>
#include <stdint.h>

// Problem: B=64, T=256, F_IN=2048, H=1024, 3H=3072, M=B*T=16384.
// d_out: output f32[64,256,1024] then hidden f32[64,1024]

typedef __bf16 bfx8 __attribute__((ext_vector_type(8)));
typedef float  f32x4 __attribute__((ext_vector_type(4)));
typedef unsigned u32x4 __attribute__((ext_vector_type(4)));
typedef unsigned long long ull;

// ---------------- fp32 -> bf16 conversion (8 elems/thread) ----------------
__global__ void cvt_bf16(const float* __restrict__ in, __bf16* __restrict__ out, int n8) {
    for (int i = blockIdx.x * blockDim.x + threadIdx.x; i < n8; i += gridDim.x * blockDim.x) {
        float4 a = ((const float4*)in)[2 * i];
        float4 b = ((const float4*)in)[2 * i + 1];
        union { __bf16 h[8]; uint4 v; } u;
        u.h[0] = (__bf16)a.x; u.h[1] = (__bf16)a.y; u.h[2] = (__bf16)a.z; u.h[3] = (__bf16)a.w;
        u.h[4] = (__bf16)b.x; u.h[5] = (__bf16)b.y; u.h[6] = (__bf16)b.z; u.h[7] = (__bf16)b.w;
        ((uint4*)out)[i] = u.v;
    }
}

// ---------------- async global->LDS 16B ----------------
__device__ __forceinline__ void g2l16(const void* g, void* l) {
    __builtin_amdgcn_global_load_lds(
        (__attribute__((address_space(1))) void*)g,
        (__attribute__((address_space(3))) void*)l,
        16, 0, 0);
}

// ---------------- m97-style bf16 GEMM: C[M][N] = A[M][K] * W[N][K]^T + bias ----------------
template <bool OUTBF16>
__global__ __launch_bounds__(256)
void gemm_bt(const __bf16* __restrict__ A, const __bf16* __restrict__ W,
             const float* __restrict__ bias, void* __restrict__ C,
             int M, int N, int K)
{
    __shared__ __bf16 As[128 * 32];
    __shared__ __bf16 Ws[128 * 32];
    const int tid  = threadIdx.x;
    const int wave = tid >> 6, lane = tid & 63;
    const int q = lane >> 4, r15 = lane & 15;
    const int n0 = blockIdx.x << 7, m0 = blockIdx.y << 7;
    const int wm = (wave >> 1) << 6, wn = (wave & 1) << 6;
    const size_t Ks = (size_t)K;
    f32x4 acc[4][4] = {};

    for (int k0 = 0; k0 < K; k0 += 32) {
        __syncthreads();
#pragma unroll
        for (int i = 0; i < 2; ++i) {
            int o  = (((i << 2) + wave) << 10);
            int ob = o + (lane << 4);
            int row = ob >> 6, colb = ob & 63;
            g2l16((const char*)A + ((size_t)(m0 + row) * Ks + k0) * 2 + colb, (char*)As + o);
            g2l16((const char*)W + ((size_t)(n0 + row) * Ks + k0) * 2 + colb, (char*)Ws + o);
        }
        __syncthreads();

        bfx8 af[4], wf[4];
#pragma unroll
        for (int mt = 0; mt < 4; ++mt)
            af[mt] = *(const bfx8*)&As[((wm + (mt << 4) + r15) << 5) + (q << 3)];
#pragma unroll
        for (int nt = 0; nt < 4; ++nt)
            wf[nt] = *(const bfx8*)&Ws[((wn + (nt << 4) + r15) << 5) + (q << 3)];
#pragma unroll
        for (int mt = 0; mt < 4; ++mt)
#pragma unroll
            for (int nt = 0; nt < 4; ++nt)
                acc[mt][nt] = __builtin_amdgcn_mfma_f32_16x16x32_bf16(af[mt], wf[nt], acc[mt][nt], 0, 0, 0);
    }

#pragma unroll
    for (int nt = 0; nt < 4; ++nt) {
        int col = n0 + wn + (nt << 4) + r15;
        float bv = bias[col];
#pragma unroll
        for (int mt = 0; mt < 4; ++mt) {
#pragma unroll
            for (int i = 0; i < 4; ++i) {
                int rrow = m0 + wm + (mt << 4) + (q << 2) + i;
                float v = acc[mt][nt][i] + bv;
                if (OUTBF16) ((__bf16*)C)[(size_t)rrow * N + col] = (__bf16)v;
                else         ((float*)C)[(size_t)rrow * N + col]  = v;
            }
        }
    }
}

// ---------------- GRU recurrence: persistent cooperative kernel ----------------
// 256 blocks = 4 batch-groups (bb, 16 batches, XCD pair) x 64 H-slices (bj).
// R5 = R4 architecture (wave-specialized sync tail; vmcnt is PER-WAVE) with
// two fixes for R4's GPU fault + wrong addressing:
//  (a) staging asm outputs are EARLY-CLOBBER ("=&v"): without it the compiler
//      may alias a load's dest regs onto a later load's address pair; data
//      landing before the later load issues => wild address => HSA abort.
//  (b) publisher uses R3-proven __hip_atomic_store (8B relaxed agent) with
//      corrected batch stride (2048B = 256 ull), then per-wave vmcnt(0),
//      then the R3-proven relaxed flag store.
__device__ __forceinline__ float sigm(float x) { return 1.f / (1.f + __expf(-x)); }
__device__ __forceinline__ float tanh_f(float x) { float e = __expf(2.f * x); return 1.f - 2.f / (e + 1.f); }

#define RP 1032  // padded LDS row stride in bf16 (2064 B)

__global__ __launch_bounds__(256, 1)
void rnn_kernel(const float* __restrict__ gx, const int* __restrict__ lens,
                const __bf16* __restrict__ whhb, const float* __restrict__ b_hh,
                ull* __restrict__ hbuf,          // [2][64][1024] bf16 = 2*16384 ull, zeroed
                float* __restrict__ out,         // B*T*H then B*H
                unsigned* __restrict__ flags)    // 256 flags, 64B apart, zeroed
{
    __shared__ __bf16 whh_s[48 * RP];
    __shared__ __bf16 hs[16 * RP];
    __shared__ float  ghs[3 * 256];
    __shared__ ull    hx[64];                    // packed h 16x16 bf16 for publication

    const int tid  = threadIdx.x;
    const int wave = tid >> 6, lane = tid & 63;
    const int q = lane >> 4, r15 = lane & 15;
    const int bb = (blockIdx.x & 7) >> 1;                         // batch group (XCD pair)
    const int bj = ((blockIdx.x >> 3) << 1) | (blockIdx.x & 1);   // unit slice 0..63

    // preload w_hh slice: LDS row (g*16+jj) <- w_hh row (g*1024 + bj*16 + jj)
    for (int i = tid; i < 6144; i += 256) {
        int row = i >> 7, c = i & 127;
        int g = row >> 4, jj = row & 15;
        uint4 v = *(const uint4*)(whhb + ((size_t)((g << 10) + (bj << 4) + jj) << 10) + (c << 3));
        *(uint4*)&whh_s[row * RP + (c << 3)] = v;
    }

    const int m_ = tid >> 4, jj_ = tid & 15;
    const int bglob = (bb << 4) + m_;
    const int jglob = (bj << 4) + jj_;
    const float bhr = b_hh[jglob], bhz = b_hh[1024 + jglob], bhn = b_hh[2048 + jglob];
    const int mylen = lens[bglob];
    const float* gp = gx + (size_t)bglob * 256 * 3072 + jglob;
    float gir = gp[0], giz = gp[1024], gin = gp[2048];   // gx for t=0
    float hstate = 0.f;
    __syncthreads();

    for (int t = 0; t < 256; ++t) {
        // ---- stage h_t (32KB): 8x dwordx4 sc1 loads/thread, EARLY-CLOBBER dests,
        //      one vmcnt batch; device-coherent (bypass stale L1/L2) ----
        {
            const char* sb = (const char*)hbuf + ((t & 1) << 17) + (bb << 15) + (tid << 4);
            u32x4 r0, r1, r2, r3, r4, r5, r6, r7;
            asm volatile(
                "global_load_dwordx4 %0, %8, off sc1\n\t"
                "global_load_dwordx4 %1, %9, off sc1\n\t"
                "global_load_dwordx4 %2, %10, off sc1\n\t"
                "global_load_dwordx4 %3, %11, off sc1\n\t"
                "global_load_dwordx4 %4, %12, off sc1\n\t"
                "global_load_dwordx4 %5, %13, off sc1\n\t"
                "global_load_dwordx4 %6, %14, off sc1\n\t"
                "global_load_dwordx4 %7, %15, off sc1\n\t"
                "s_waitcnt vmcnt(0)"
                : "=&v"(r0), "=&v"(r1), "=&v"(r2), "=&v"(r3),
                  "=&v"(r4), "=&v"(r5), "=&v"(r6), "=&v"(r7)
                : "v"(sb),          "v"(sb + 4096),  "v"(sb + 8192),  "v"(sb + 12288),
                  "v"(sb + 16384),  "v"(sb + 20480), "v"(sb + 24576), "v"(sb + 28672)
                : "memory");
            // chunk c = tid + k*256: LDS row m = 2k + (tid>>7), col16 = tid&127
            const int colb = (tid & 127) << 4;
            const int mh = tid >> 7;
            char* hsb = (char*)hs;
            *(u32x4*)(hsb + (2 * 0 + mh) * 2064 + colb) = r0;
            *(u32x4*)(hsb + (2 * 1 + mh) * 2064 + colb) = r1;
            *(u32x4*)(hsb + (2 * 2 + mh) * 2064 + colb) = r2;
            *(u32x4*)(hsb + (2 * 3 + mh) * 2064 + colb) = r3;
            *(u32x4*)(hsb + (2 * 4 + mh) * 2064 + colb) = r4;
            *(u32x4*)(hsb + (2 * 5 + mh) * 2064 + colb) = r5;
            *(u32x4*)(hsb + (2 * 6 + mh) * 2064 + colb) = r6;
            *(u32x4*)(hsb + (2 * 7 + mh) * 2064 + colb) = r7;
        }
        __syncthreads();

        // waves 0..2: gate g = wave; D[16 batch][16 units] = h(16x1024) @ w_hh^T
        if (wave < 3) {
            f32x4 acc = {0.f, 0.f, 0.f, 0.f};
            const __bf16* wrow = &whh_s[(wave * 16 + r15) * RP];
            const __bf16* hrow = &hs[r15 * RP];
#pragma unroll
            for (int kk = 0; kk < 32; ++kk) {
                bfx8 a = *(const bfx8*)(hrow + (kk << 5) + (q << 3));
                bfx8 b = *(const bfx8*)(wrow + (kk << 5) + (q << 3));
                acc = __builtin_amdgcn_mfma_f32_16x16x32_bf16(a, b, acc, 0, 0, 0);
            }
#pragma unroll
            for (int i2 = 0; i2 < 4; ++i2)
                ghs[wave * 256 + (((q << 2) + i2) << 4) + r15] = acc[i2];
        }
        __syncthreads();

        // gates: thread <-> (batch m_, unit jj_)
        float ghr = ghs[tid] + bhr;
        float ghz = ghs[256 + tid] + bhz;
        float ghn = ghs[512 + tid] + bhn;
        float rg = sigm(gir + ghr);
        float zg = sigm(giz + ghz);
        float ng = tanh_f(gin + rg * ghn);
        float hnew = (1.f - zg) * ng + zg * hstate;
        bool mk = t < mylen;
        hstate = mk ? hnew : hstate;
        float y = mk ? hnew : 0.f;

        if (t < 255) {
            // pack h (bf16) into LDS for the publisher wave
            ((__bf16*)hx)[(m_ << 4) + jj_] = (__bf16)hstate;
            __syncthreads();  // barrier#1: hx visible

            if (wave == 3) {
                // publisher: ONE 8B relaxed agent store/lane (R3-proven coherent path),
                // wait ONLY this wave's vmem (the publish store), then flag.
                int m = lane >> 2, c = lane & 3;          // batch, unit-quad
                ull hv = hx[lane];
                // ull index: parity*16384 + batch*256 + bj*4 + c   (2048B/batch)
                ull* pa = hbuf + (((t + 1) & 1) << 14)
                        + (((bb << 4) + m) << 8) + (bj << 2) + c;
                __hip_atomic_store(pa, hv, __ATOMIC_RELAXED, __HIP_MEMORY_SCOPE_AGENT);
                asm volatile("" ::: "memory");
                __builtin_amdgcn_s_waitcnt(0x0F70);  // vmcnt(0) only (per-wave)
                asm volatile("" ::: "memory");
                if (lane == 0)
                    __hip_atomic_store(&flags[blockIdx.x << 4], (unsigned)(t + 1),
                                       __ATOMIC_RELAXED, __HIP_MEMORY_SCOPE_AGENT);
            }

            // out store + gx(t+1) prefetch AFTER barrier#1: their latency drains
            // under the publish/poll window instead of gating the flag.
            out[(size_t)(bglob * 256 + t) * 1024 + jglob] = y;
            gp += 3072;
            gir = gp[0]; giz = gp[1024]; gin = gp[2048];

            if (wave == 0) {
                // lane l polls producer ((l>>1)*8 + 2bb + (l&1)) — group bb's 64 blocks
                int pid = ((lane >> 1) << 3) + (bb << 1) + (lane & 1);
                const unsigned* fp = &flags[pid << 4];
                unsigned tgt = (unsigned)(t + 1);
                while (__hip_atomic_load(fp, __ATOMIC_RELAXED, __HIP_MEMORY_SCOPE_AGENT) < tgt)
                    __builtin_amdgcn_s_sleep(1);
                asm volatile("" ::: "memory");  // keep stage loads after the poll
            }
            __syncthreads();  // barrier#2
        } else {
            out[(size_t)(bglob * 256 + t) * 1024 + jglob] = y;
            out[(size_t)(64 * 256) * 1024 + ((size_t)bglob << 10) + jglob] = y;  // hidden
        }
    }
}

// ---------------- launch ----------------
extern "C" void kernel_launch(void* const* d_in, const int* in_sizes, int n_in,
                              void* d_out, int out_size, void* d_ws, size_t ws_size,
                              hipStream_t stream) {
    const float* input = (const float*)d_in[0];
    const int*   lens  = (const int*)d_in[1];
    const float* W_p   = (const float*)d_in[2];
    const float* b_p   = (const float*)d_in[3];
    const float* w_ih  = (const float*)d_in[4];
    const float* w_hh  = (const float*)d_in[5];
    const float* b_ih  = (const float*)d_in[6];
    const float* b_hh  = (const float*)d_in[7];
    float* out = (float*)d_out;
    char* ws = (char*)d_ws;

    // workspace layout (bytes): total ~319 MB
    __bf16* Xb   = (__bf16*)(ws + 0);            // 67,108,864
    __bf16* Wpb  = (__bf16*)(ws + 67108864);     //  4,194,304
    __bf16* wihb = (__bf16*)(ws + 71303168);     //  6,291,456
    __bf16* whhb = (__bf16*)(ws + 77594624);     //  6,291,456
    __bf16* embb = (__bf16*)(ws + 83886080);     // 33,554,432
    float*  gx   = (float*) (ws + 117440512);    // 201,326,592
    ull* hbuf    = (ull*)(ws + 318767104);       // 262,144 (double-buffered h)
    unsigned* flags = (unsigned*)(ws + 319029248); // 256 x 64B = 16,384

    // zero h state + flags (d_ws is poisoned 0xAA before every launch)
    hipMemsetAsync(ws + 318767104, 0, 262144 + 16384, stream);

    cvt_bf16<<<4096, 256, 0, stream>>>(input, Xb, 33554432 / 8);
    cvt_bf16<<<1024, 256, 0, stream>>>(W_p,  Wpb, 2097152 / 8);
    cvt_bf16<<<1536, 256, 0, stream>>>(w_ih, wihb, 3145728 / 8);
    cvt_bf16<<<1536, 256, 0, stream>>>(w_hh, whhb, 3145728 / 8);

    // emb = X @ W_p^T + b_p  (bf16 out), M=16384 N=1024 K=2048
    gemm_bt<true><<<dim3(8, 128), 256, 0, stream>>>(Xb, Wpb, b_p, embb, 16384, 1024, 2048);
    // gx = emb @ w_ih^T + b_ih (f32 out), M=16384 N=3072 K=1024
    gemm_bt<false><<<dim3(24, 128), 256, 0, stream>>>(embb, wihb, b_ih, gx, 16384, 3072, 1024);

    // recurrence: 256 blocks (1 block/CU, co-resident), 256 steps
    rnn_kernel<<<256, 256, 0, stream>>>(gx, lens, whhb, b_hh, hbuf, out, flags);
}

// Round 6
// 1048.470 us; speedup vs baseline: 3.8346x; 1.3164x over previous
//
#include <hip/hip_runtime.h>
#include <stdint.h>

// Problem: B=64, T=256, F_IN=2048, H=1024, 3H=3072, M=B*T=16384.
// d_out: output f32[64,256,1024] then hidden f32[64,1024]

typedef __bf16 bfx8 __attribute__((ext_vector_type(8)));
typedef float  f32x4 __attribute__((ext_vector_type(4)));
typedef unsigned u32x4 __attribute__((ext_vector_type(4)));
typedef unsigned long long ull;

// ---------------- fp32 -> bf16 conversion (8 elems/thread) ----------------
__global__ void cvt_bf16(const float* __restrict__ in, __bf16* __restrict__ out, int n8) {
    for (int i = blockIdx.x * blockDim.x + threadIdx.x; i < n8; i += gridDim.x * blockDim.x) {
        float4 a = ((const float4*)in)[2 * i];
        float4 b = ((const float4*)in)[2 * i + 1];
        union { __bf16 h[8]; uint4 v; } u;
        u.h[0] = (__bf16)a.x; u.h[1] = (__bf16)a.y; u.h[2] = (__bf16)a.z; u.h[3] = (__bf16)a.w;
        u.h[4] = (__bf16)b.x; u.h[5] = (__bf16)b.y; u.h[6] = (__bf16)b.z; u.h[7] = (__bf16)b.w;
        ((uint4*)out)[i] = u.v;
    }
}

// ---------------- async global->LDS 16B ----------------
__device__ __forceinline__ void g2l16(const void* g, void* l) {
    __builtin_amdgcn_global_load_lds(
        (__attribute__((address_space(1))) void*)g,
        (__attribute__((address_space(3))) void*)l,
        16, 0, 0);
}

// ---------------- m97-style bf16 GEMM: C[M][N] = A[M][K] * W[N][K]^T + bias ----------------
template <bool OUTBF16>
__global__ __launch_bounds__(256)
void gemm_bt(const __bf16* __restrict__ A, const __bf16* __restrict__ W,
             const float* __restrict__ bias, void* __restrict__ C,
             int M, int N, int K)
{
    __shared__ __bf16 As[128 * 32];
    __shared__ __bf16 Ws[128 * 32];
    const int tid  = threadIdx.x;
    const int wave = tid >> 6, lane = tid & 63;
    const int q = lane >> 4, r15 = lane & 15;
    const int n0 = blockIdx.x << 7, m0 = blockIdx.y << 7;
    const int wm = (wave >> 1) << 6, wn = (wave & 1) << 6;
    const size_t Ks = (size_t)K;
    f32x4 acc[4][4] = {};

    for (int k0 = 0; k0 < K; k0 += 32) {
        __syncthreads();
#pragma unroll
        for (int i = 0; i < 2; ++i) {
            int o  = (((i << 2) + wave) << 10);
            int ob = o + (lane << 4);
            int row = ob >> 6, colb = ob & 63;
            g2l16((const char*)A + ((size_t)(m0 + row) * Ks + k0) * 2 + colb, (char*)As + o);
            g2l16((const char*)W + ((size_t)(n0 + row) * Ks + k0) * 2 + colb, (char*)Ws + o);
        }
        __syncthreads();

        bfx8 af[4], wf[4];
#pragma unroll
        for (int mt = 0; mt < 4; ++mt)
            af[mt] = *(const bfx8*)&As[((wm + (mt << 4) + r15) << 5) + (q << 3)];
#pragma unroll
        for (int nt = 0; nt < 4; ++nt)
            wf[nt] = *(const bfx8*)&Ws[((wn + (nt << 4) + r15) << 5) + (q << 3)];
#pragma unroll
        for (int mt = 0; mt < 4; ++mt)
#pragma unroll
            for (int nt = 0; nt < 4; ++nt)
                acc[mt][nt] = __builtin_amdgcn_mfma_f32_16x16x32_bf16(af[mt], wf[nt], acc[mt][nt], 0, 0, 0);
    }

#pragma unroll
    for (int nt = 0; nt < 4; ++nt) {
        int col = n0 + wn + (nt << 4) + r15;
        float bv = bias[col];
#pragma unroll
        for (int mt = 0; mt < 4; ++mt) {
#pragma unroll
            for (int i = 0; i < 4; ++i) {
                int rrow = m0 + wm + (mt << 4) + (q << 2) + i;
                float v = acc[mt][nt][i] + bv;
                if (OUTBF16) ((__bf16*)C)[(size_t)rrow * N + col] = (__bf16)v;
                else         ((float*)C)[(size_t)rrow * N + col]  = v;
            }
        }
    }
}

// ---------------- GRU recurrence: persistent cooperative kernel ----------------
// 256 blocks = 4 batch-groups (bb, 16 batches, XCD pair) x 64 H-slices (bj).
// R6 restructure (R5 sync model proven — keep the flag/sc1 coherence paths):
//  1. w_hh B-fragments live in REGISTERS (96 VGPR; occupancy is 1 blk/CU so
//     VGPRs to 512 are free) — no whh LDS, no B ds_reads in the loop.
//  2. Split-K across ALL 4 waves: each wave K-chunk=256, 3 gates x 8-deep
//     independent MFMA chains (pipelined), 12KB LDS partial reduce.
//  3. Publish: every thread owns one h value; shfl_xor-pair, even lanes one
//     4B relaxed-agent store; __syncthreads (per-wave vmcnt drain) = ack.
//  4. Stage: per-thread poll of its OWN producer's flag ((tid&127)>>1) gates
//     its own 8 sc1 loads — no central poll+barrier; skew-adaptive.
//  3 barriers/step (was 4).
__device__ __forceinline__ float sigm(float x) { return 1.f / (1.f + __expf(-x)); }
__device__ __forceinline__ float tanh_f(float x) { float e = __expf(2.f * x); return 1.f - 2.f / (e + 1.f); }

#define RP 1032  // padded LDS row stride in bf16 (2064 B; 16B-pad => 2-way banks, free)

__global__ __launch_bounds__(256, 1)
void rnn_kernel(const float* __restrict__ gx, const int* __restrict__ lens,
                const __bf16* __restrict__ whhb, const float* __restrict__ b_hh,
                char* __restrict__ hbuf,         // [2][64][1024] bf16 = 256KB, zeroed
                float* __restrict__ out,         // B*T*H then B*H
                unsigned* __restrict__ flags)    // 256 flags, 64B apart, zeroed
{
    __shared__ __bf16 hs[16 * RP];               // staged h: 16 batches x 1024 (33KB)
    __shared__ float  ghs2[3 * 4 * 256];         // gate partials [g][wave][m*16+n] (12KB)

    const int tid  = threadIdx.x;
    const int wave = tid >> 6, lane = tid & 63;
    const int q = lane >> 4, r15 = lane & 15;
    const int bb = (blockIdx.x & 7) >> 1;                         // batch group (XCD pair)
    const int bj = ((blockIdx.x >> 3) << 1) | (blockIdx.x & 1);   // unit slice 0..63

    // ---- one-time: w_hh B-fragments into registers ----
    // gate g, kk: B[n=r15][k = wave*256 + kk*32 + q*8 .. +7], row = g*1024+bj*16+r15
    bfx8 Bf[3][8];
#pragma unroll
    for (int g = 0; g < 3; ++g)
#pragma unroll
        for (int kk = 0; kk < 8; ++kk)
            Bf[g][kk] = *(const bfx8*)(whhb
                + ((size_t)((g << 10) + (bj << 4) + r15) << 10)
                + (wave << 8) + (kk << 5) + (q << 3));

    const int m_ = tid >> 4, jj_ = tid & 15;
    const int bglob = (bb << 4) + m_;
    const int jglob = (bj << 4) + jj_;
    const float bhr = b_hh[jglob], bhz = b_hh[1024 + jglob], bhn = b_hh[2048 + jglob];
    const int mylen = lens[bglob];
    // my staging producer: unit-slice pd = (tid&127)>>1 -> its blockIdx
    const int pd   = (tid & 127) >> 1;
    const int pblk = ((pd >> 1) << 3) | (bb << 1) | (pd & 1);
    const unsigned* fpoll = &flags[pblk << 4];

    const float* gp = gx + (size_t)bglob * 256 * 3072 + jglob;
    float gir = gp[0], giz = gp[1024], gin = gp[2048];   // gx for t=0
    float hstate = 0.f;

    for (int t = 0; t < 256; ++t) {
        // ---- per-thread: wait own producer, then stage its 8 chunks (sc1) ----
        if (t > 0) {
            unsigned tgt = (unsigned)t;
            while (__hip_atomic_load(fpoll, __ATOMIC_RELAXED, __HIP_MEMORY_SCOPE_AGENT) < tgt)
                __builtin_amdgcn_s_sleep(1);
            asm volatile("" ::: "memory");
        }
        {
            const char* sb = hbuf + ((t & 1) << 17) + (bb << 15) + (tid << 4);
            u32x4 r0, r1, r2, r3, r4, r5, r6, r7;
            asm volatile(
                "global_load_dwordx4 %0, %8, off sc1\n\t"
                "global_load_dwordx4 %1, %9, off sc1\n\t"
                "global_load_dwordx4 %2, %10, off sc1\n\t"
                "global_load_dwordx4 %3, %11, off sc1\n\t"
                "global_load_dwordx4 %4, %12, off sc1\n\t"
                "global_load_dwordx4 %5, %13, off sc1\n\t"
                "global_load_dwordx4 %6, %14, off sc1\n\t"
                "global_load_dwordx4 %7, %15, off sc1\n\t"
                "s_waitcnt vmcnt(0)"
                : "=&v"(r0), "=&v"(r1), "=&v"(r2), "=&v"(r3),
                  "=&v"(r4), "=&v"(r5), "=&v"(r6), "=&v"(r7)
                : "v"(sb),          "v"(sb + 4096),  "v"(sb + 8192),  "v"(sb + 12288),
                  "v"(sb + 16384),  "v"(sb + 20480), "v"(sb + 24576), "v"(sb + 28672)
                : "memory");
            const int colb = (tid & 127) << 4;
            const int mh = tid >> 7;
            char* hsb = (char*)hs;
            *(u32x4*)(hsb + (2 * 0 + mh) * 2064 + colb) = r0;
            *(u32x4*)(hsb + (2 * 1 + mh) * 2064 + colb) = r1;
            *(u32x4*)(hsb + (2 * 2 + mh) * 2064 + colb) = r2;
            *(u32x4*)(hsb + (2 * 3 + mh) * 2064 + colb) = r3;
            *(u32x4*)(hsb + (2 * 4 + mh) * 2064 + colb) = r4;
            *(u32x4*)(hsb + (2 * 5 + mh) * 2064 + colb) = r5;
            *(u32x4*)(hsb + (2 * 6 + mh) * 2064 + colb) = r6;
            *(u32x4*)(hsb + (2 * 7 + mh) * 2064 + colb) = r7;
        }
        __syncthreads();  // barB: h staged

        // ---- all 4 waves: K-chunk = wave*256, 3 gates, 8-deep pipelined chains ----
        {
            f32x4 a0 = {0.f, 0.f, 0.f, 0.f}, a1 = a0, a2 = a0;
            const __bf16* hrow = &hs[r15 * RP + (wave << 8)];
#pragma unroll
            for (int kk = 0; kk < 8; ++kk) {
                bfx8 a = *(const bfx8*)(hrow + (kk << 5) + (q << 3));
                a0 = __builtin_amdgcn_mfma_f32_16x16x32_bf16(a, Bf[0][kk], a0, 0, 0, 0);
                a1 = __builtin_amdgcn_mfma_f32_16x16x32_bf16(a, Bf[1][kk], a1, 0, 0, 0);
                a2 = __builtin_amdgcn_mfma_f32_16x16x32_bf16(a, Bf[2][kk], a2, 0, 0, 0);
            }
#pragma unroll
            for (int i2 = 0; i2 < 4; ++i2) {
                int di = (((q << 2) + i2) << 4) + r15;   // m*16 + n
                ghs2[(wave << 8) + di]        = a0[i2];
                ghs2[1024 + (wave << 8) + di] = a1[i2];
                ghs2[2048 + (wave << 8) + di] = a2[i2];
            }
        }
        __syncthreads();  // barC: partials ready

        // ---- reduce 4 partials + gates; thread <-> (batch m_, unit jj_) ----
        float ghr = ghs2[tid] + ghs2[256 + tid] + ghs2[512 + tid] + ghs2[768 + tid] + bhr;
        float ghz = ghs2[1024 + tid] + ghs2[1280 + tid] + ghs2[1536 + tid] + ghs2[1792 + tid] + bhz;
        float ghn = ghs2[2048 + tid] + ghs2[2304 + tid] + ghs2[2560 + tid] + ghs2[2816 + tid] + bhn;
        float rg = sigm(gir + ghr);
        float zg = sigm(giz + ghz);
        float ng = tanh_f(gin + rg * ghn);
        float hnew = (1.f - zg) * ng + zg * hstate;
        bool mk = t < mylen;
        hstate = mk ? hnew : hstate;
        float y = mk ? hnew : 0.f;

        if (t < 255) {
            // ---- publish: pair-pack via shfl, even lanes one 4B coherent store ----
            union { unsigned short us; __bf16 h; } cv; cv.h = (__bf16)hstate;
            unsigned hb = cv.us;
            unsigned nb = (unsigned)__shfl_xor((int)hb, 1);
            if (!(tid & 1)) {
                unsigned dv = hb | (nb << 16);
                unsigned* hw = (unsigned*)(hbuf + (((t + 1) & 1) << 17)
                             + (bglob << 11) + ((bj << 4) + jj_) * 2);
                __hip_atomic_store(hw, dv, __ATOMIC_RELAXED, __HIP_MEMORY_SCOPE_AGENT);
            }
            __syncthreads();  // barA: per-wave vmcnt(0) => all h stores acked at LLC
            if (tid == 0)
                __hip_atomic_store(&flags[blockIdx.x << 4], (unsigned)(t + 1),
                                   __ATOMIC_RELAXED, __HIP_MEMORY_SCOPE_AGENT);
            // out store + gx(t+1) prefetch: drain under next poll/stage window
            out[(size_t)(bglob * 256 + t) * 1024 + jglob] = y;
            gp += 3072;
            gir = gp[0]; giz = gp[1024]; gin = gp[2048];
        } else {
            out[(size_t)(bglob * 256 + t) * 1024 + jglob] = y;
            out[(size_t)(64 * 256) * 1024 + ((size_t)bglob << 10) + jglob] = y;  // hidden
        }
    }
}

// ---------------- launch ----------------
extern "C" void kernel_launch(void* const* d_in, const int* in_sizes, int n_in,
                              void* d_out, int out_size, void* d_ws, size_t ws_size,
                              hipStream_t stream) {
    const float* input = (const float*)d_in[0];
    const int*   lens  = (const int*)d_in[1];
    const float* W_p   = (const float*)d_in[2];
    const float* b_p   = (const float*)d_in[3];
    const float* w_ih  = (const float*)d_in[4];
    const float* w_hh  = (const float*)d_in[5];
    const float* b_ih  = (const float*)d_in[6];
    const float* b_hh  = (const float*)d_in[7];
    float* out = (float*)d_out;
    char* ws = (char*)d_ws;

    // workspace layout (bytes): total ~319 MB
    __bf16* Xb   = (__bf16*)(ws + 0);            // 67,108,864
    __bf16* Wpb  = (__bf16*)(ws + 67108864);     //  4,194,304
    __bf16* wihb = (__bf16*)(ws + 71303168);     //  6,291,456
    __bf16* whhb = (__bf16*)(ws + 77594624);     //  6,291,456
    __bf16* embb = (__bf16*)(ws + 83886080);     // 33,554,432
    float*  gx   = (float*) (ws + 117440512);    // 201,326,592
    char* hbuf   = ws + 318767104;               // 262,144 (double-buffered h)
    unsigned* flags = (unsigned*)(ws + 319029248); // 256 x 64B = 16,384

    // zero h state + flags (d_ws is poisoned 0xAA before every launch)
    hipMemsetAsync(ws + 318767104, 0, 262144 + 16384, stream);

    cvt_bf16<<<4096, 256, 0, stream>>>(input, Xb, 33554432 / 8);
    cvt_bf16<<<1024, 256, 0, stream>>>(W_p,  Wpb, 2097152 / 8);
    cvt_bf16<<<1536, 256, 0, stream>>>(w_ih, wihb, 3145728 / 8);
    cvt_bf16<<<1536, 256, 0, stream>>>(w_hh, whhb, 3145728 / 8);

    // emb = X @ W_p^T + b_p  (bf16 out), M=16384 N=1024 K=2048
    gemm_bt<true><<<dim3(8, 128), 256, 0, stream>>>(Xb, Wpb, b_p, embb, 16384, 1024, 2048);
    // gx = emb @ w_ih^T + b_ih (f32 out), M=16384 N=3072 K=1024
    gemm_bt<false><<<dim3(24, 128), 256, 0, stream>>>(embb, wihb, b_ih, gx, 16384, 3072, 1024);

    // recurrence: 256 blocks (1 block/CU, co-resident), 256 steps
    rnn_kernel<<<256, 256, 0, stream>>>(gx, lens, whhb, b_hh, hbuf, out, flags);
}